// Round 8
// baseline (631.894 us; speedup 1.0000x reference)
//
#include <hip/hip_runtime.h>
#include <hip/hip_fp16.h>

typedef _Float16 half_t;
typedef _Float16 half8 __attribute__((ext_vector_type(8)));
typedef float floatx4 __attribute__((ext_vector_type(4)));
typedef int   int4v  __attribute__((ext_vector_type(4)));

// ---- sizes ----
#define T_STEPS 300
#define NMB     1024                 // N*M batch

// ws layout (bytes)
#define XT_OFF   0ULL
#define XT_BYTES ((unsigned long long)(T_STEPS*NMB + 16)*64*2)
#define WCH_OFF  (XT_OFF + XT_BYTES)          // wcomb f16 [512][64], col45 = bias

// L_hat = -D^-1/2 A D^-1/2 for the hardcoded 15-node skeleton (row=dst, col=src)
#define S2 0.70710678118654752f
#define QH 0.5f
#define UU 0.40824829046386302f
#define TH 0.33333333333333333f
__constant__ float LHAT[225] = {
  0,0,-S2,0,0,0,0,0,0,0,0,0,0,0,0,
  0,0,0,-S2,0,0,0,0,0,0,0,0,0,0,0,
  -S2,0,0,0,-QH,0,0,0,0,0,0,0,0,0,0,
  0,-S2,0,0,0,-QH,0,0,0,0,0,0,0,0,0,
  0,0,-QH,0,0,0,0,0,0,0,0,0,0,0,-UU,
  0,0,0,-QH,0,0,0,0,0,0,0,0,0,0,-UU,
  0,0,0,0,0,0,0,0,-S2,0,0,0,0,0,0,
  0,0,0,0,0,0,0,0,0,-S2,0,0,0,0,0,
  0,0,0,0,0,0,-S2,0,0,0,-QH,0,0,0,0,
  0,0,0,0,0,0,0,-S2,0,0,0,-QH,0,0,0,
  0,0,0,0,0,0,0,0,-QH,0,0,0,0,-UU,0,
  0,0,0,0,0,0,0,0,0,-QH,0,0,0,-UU,0,
  0,0,0,0,0,0,0,0,0,0,0,0,0,0,0,
  0,0,0,0,0,0,0,0,0,0,-UU,-UU,0,0,0,
  0,0,0,0,-UU,-UU,0,0,0,0,0,0,0,-TH,0
};

// Fast gate math: v_exp_f32 + v_rcp_f32 (approx, ~1 ulp).
__device__ __forceinline__ float frcp(float x)  { return __builtin_amdgcn_rcpf(x); }
__device__ __forceinline__ float fsig(float x)  { return frcp(1.f + __expf(-x)); }
__device__ __forceinline__ float ftanh(float x) { return 2.f*frcp(1.f + __expf(-2.f*x)) - 1.f; }

__device__ __forceinline__ half8 load_w8(const float* p) {
  const float4* q = (const float4*)p;
  float4 a = q[0], b = q[1];
  half8 f;
  f[0]=(half_t)a.x; f[1]=(half_t)a.y; f[2]=(half_t)a.z; f[3]=(half_t)a.w;
  f[4]=(half_t)b.x; f[5]=(half_t)b.y; f[6]=(half_t)b.z; f[7]=(half_t)b.w;
  return f;
}

// Force true register residency of fragments (kills per-step remat).
__device__ __forceinline__ void pin(half8& f) {
  int4v t = __builtin_bit_cast(int4v, f);
  asm volatile("" : "+v"(t));
  f = __builtin_bit_cast(half8, t);
}
__device__ __forceinline__ void pinf(floatx4& f) {
  int4v t = __builtin_bit_cast(int4v, f);
  asm volatile("" : "+v"(t));
  f = __builtin_bit_cast(floatx4, t);
}

// ---- K0: fold ChebConv into layer-0 input projection.
// wcomb_h f16[512][64]; col 45 holds the combined layer-0 bias (paired with a
// constant-1.0 x column 45 written by k_xpose) so xproj MFMA folds the bias free.
__global__ void k_prep(const float* __restrict__ w0, const float* __restrict__ w1,
                       const float* __restrict__ cb, const float* __restrict__ wih0,
                       const float* __restrict__ bih0, const float* __restrict__ bhh0,
                       half_t* __restrict__ wcomb_h) {
  const int n = threadIdx.x; // 512 threads, 1 block
  float wrow[45];
  #pragma unroll
  for (int i=0;i<45;i++) wrow[i] = wih0[n*45+i];
  float P[45];
  #pragma unroll
  for (int i=0;i<15;i++)
    #pragma unroll
    for (int c=0;c<3;c++) {
      float s = 0.f;
      #pragma unroll
      for (int cp=0;cp<3;cp++) s += wrow[i*3+cp]*w1[cp*3+c];
      P[i*3+c] = s;
    }
  #pragma unroll
  for (int j=0;j<15;j++)
    #pragma unroll
    for (int c=0;c<3;c++) {
      float s = 0.f;
      #pragma unroll
      for (int cp=0;cp<3;cp++) s += wrow[j*3+cp]*w0[cp*3+c];
      #pragma unroll
      for (int i=0;i<15;i++) s += LHAT[i*15+j]*P[i*3+c];
      wcomb_h[n*64 + j*3+c] = (half_t)s;
    }
  float b = bih0[n] + bhh0[n];
  #pragma unroll
  for (int i=0;i<15;i++)
    #pragma unroll
    for (int cp=0;cp<3;cp++) b += wrow[i*3+cp]*cb[cp];
  wcomb_h[n*64 + 45] = (half_t)b;
  for (int k=46;k<64;k++) wcomb_h[n*64+k] = (half_t)0.f;
}

// ---- K0b: x1 [N,C,T,V,M] fp32 -> xt [t*1024+nm][64] fp16 (features v*3+c).
// Also writes col45=1.0 (bias lane) and zeros cols 46..63 (MFMA-safe).
__global__ void k_xpose(const float* __restrict__ x1, half_t* __restrict__ xt) {
  const int id = blockIdx.x*256 + threadIdx.x;   // exactly 512*3*300*15 = 6,912,000
  const int v  = id % 15;
  const int r1 = id / 15;
  const int t  = r1 % 300;
  const int r2 = r1 / 300;
  const int c  = r2 % 3;
  const int n  = r2 / 3;
  const float2 f = ((const float2*)x1)[id];      // m=0,1 pair, coalesced
  const size_t row = (size_t)t*NMB + n*2;
  xt[row*64     + v*3 + c] = (half_t)f.x;
  xt[(row+1)*64 + v*3 + c] = (half_t)f.y;
  if (c==0 && v==0) {
    #pragma unroll
    for (int k=45;k<64;k++) {
      const half_t z = (half_t)((k==45)?1.f:0.f);
      xt[row*64+k] = z; xt[(row+1)*64+k] = z;
    }
  }
}

// ---- Merged both-layer LSTM: 256 WGs x 512 threads, 1 WG/CU (80KB LDS).
// Each WG owns 4 batch rows and runs BOTH layers, l1 one step behind l0, in the
// same instruction stream between the same barriers: two independent
// ds_read->MFMA->gate chains interleave, hiding each other's latency (R5-R7
// showed 35% pure stall from a single lockstep chain).  hs0 global traffic,
// flags and cross-CU handoff are GONE: l1 reads h0 directly from the l0 LDS
// ring (depth 2).
// Geometry (R1-verified M=4 pattern, per layer): A row m = [batch m&3]; C reg
// r = batch r (quad-redundant); lane (quad,l16) owns (batch=quad, col=colw).
// Weights: whh0/wih1/whh1 fragments pinned in VGPRs (192); wcomb in LDS
// (xproj-only, off the recurrent path); l0 bias folded via x col45=1.0.
// x path: wave 0 stages step i+1 into a 2-slot LDS ring (reg-staged, 1 ahead);
// all slot reuse is separated by >=1 barrier.
__launch_bounds__(512, 1)
__global__ void k_lstm_m(const half_t* __restrict__ xt, const half_t* __restrict__ wch,
                         const float* __restrict__ whh0, const float* __restrict__ wih1,
                         const float* __restrict__ whh1, const float* __restrict__ bih1,
                         const float* __restrict__ bhh1, const float* __restrict__ fcw,
                         const float* __restrict__ fcb, float* __restrict__ out) {
  __shared__ __align__(16) half_t wcl[512][72];     // 73728 B (cols 64..71 pad, unread)
  __shared__ __align__(16) half_t xr[2][4][64];     //  1024 B
  __shared__ __align__(16) half_t hr[2][4][144];    //  2304 B  h0 ring
  __shared__ __align__(16) half_t h2[2][4][144];    //  2304 B  h1 ring
  __shared__ float logits[240];                     //   960 B
  const int tid = threadIdx.x;
  const int wave = tid>>6, lane = tid&63, quad = lane>>4, l16 = lane&15;
  const int colw = wave*16 + l16;                   // owned h column
  const int nm0 = blockIdx.x*4;

  // wch -> LDS (one 64-half row per thread; wcl pitch 72 = 36 dw, good bank spread)
  {
    const float4* s = (const float4*)(wch + tid*64);
    float4* d = (float4*)&wcl[tid][0];
    #pragma unroll
    for (int k=0;k<8;k++) d[k] = s[k];
  }
  for (int i=tid; i<2*4*144; i+=512) { (&hr[0][0][0])[i] = (half_t)0.f; (&h2[0][0][0])[i] = (half_t)0.f; }

  half8 whhF[4][4], wxF[4][4], whF[4][4]; float bias1[4];
  #pragma unroll
  for (int nt=0; nt<4; nt++) {
    const int gcol = nt*128 + colw;
    #pragma unroll
    for (int kc=0; kc<4; kc++) {
      whhF[nt][kc] = load_w8(whh0 + gcol*128 + kc*32 + quad*8); pin(whhF[nt][kc]);
      wxF [nt][kc] = load_w8(wih1 + gcol*128 + kc*32 + quad*8); pin(wxF [nt][kc]);
      whF [nt][kc] = load_w8(whh1 + gcol*128 + kc*32 + quad*8); pin(whF [nt][kc]);
    }
    bias1[nt] = bih1[gcol] + bhh1[gcol];
  }
  floatx4 z4 = {0.f,0.f,0.f,0.f}; pinf(z4);
  float cst0 = 0.f, cst1 = 0.f;

  // x stage prologue: x(0) -> xr[0]; x(1) -> regs
  float4 xldr;
  if (wave==0 && lane<32) {
    float4 a = *(const float4*)(xt + (size_t)nm0*64 + lane*8);
    xldr     = *(const float4*)(xt + ((size_t)1*NMB + nm0)*64 + lane*8);
    *(float4*)((half_t*)&xr[0][0][0] + lane*8) = a;
  }
  __syncthreads();

  for (int i=0; i<=T_STEPS; i++) {
    const int cur = i&1, nxt = cur^1;
    if (i < T_STEPS) {
      // stage x(i+1) into xr[nxt] (slot last read at interval i-1); load x(i+2)
      if (wave==0 && lane<32) {
        if (i <= T_STEPS-2) *(float4*)((half_t*)&xr[nxt][0][0] + lane*8) = xldr;
        if (i <= T_STEPS-3) xldr = *(const float4*)(xt + ((size_t)(i+2)*NMB + nm0)*64 + lane*8);
      }
      // ---- l0 xproj (C-init z4; bias arrives via x col45 * wch col45)
      floatx4 xp0[4];
      {
        const half_t* xrow = &xr[cur][l16&3][0];
        half8 xa0 = *(const half8*)(xrow + quad*8);
        half8 xa1 = *(const half8*)(xrow + 32 + quad*8);
        #pragma unroll
        for (int nt=0; nt<4; nt++) {
          const half_t* wr = &wcl[nt*128 + colw][0];
          half8 w0 = *(const half8*)(wr + quad*8);
          half8 w1 = *(const half8*)(wr + 32 + quad*8);
          floatx4 a = __builtin_amdgcn_mfma_f32_16x16x32_f16(xa0, w0, z4, 0,0,0);
          xp0[nt]   = __builtin_amdgcn_mfma_f32_16x16x32_f16(xa1, w1, a, 0,0,0);
        }
      }
      // ---- l0 recurrent chain, C-init xp0
      floatx4 ah[4];
      {
        const half_t* hrow = &hr[nxt][l16&3][0];
        half8 ha[4];
        #pragma unroll
        for (int kc=0; kc<4; kc++) ha[kc] = *(const half8*)(hrow + kc*32 + quad*8);
        #pragma unroll
        for (int nt=0; nt<4; nt++) {
          floatx4 a = __builtin_amdgcn_mfma_f32_16x16x32_f16(ha[0], whhF[nt][0], xp0[nt], 0,0,0);
          a = __builtin_amdgcn_mfma_f32_16x16x32_f16(ha[1], whhF[nt][1], a, 0,0,0);
          a = __builtin_amdgcn_mfma_f32_16x16x32_f16(ha[2], whhF[nt][2], a, 0,0,0);
          ah[nt] = __builtin_amdgcn_mfma_f32_16x16x32_f16(ha[3], whhF[nt][3], a, 0,0,0);
        }
      }
      cst0 = fsig(ah[1][quad])*cst0 + fsig(ah[0][quad])*ftanh(ah[2][quad]);
      hr[cur][quad][colw] = (half_t)(fsig(ah[3][quad])*ftanh(cst0));
    }
    if (i >= 1) {
      // ---- l1 step i-1: input h0(i-1) = hr[nxt]; state h1(i-2) = h2[nxt]
      floatx4 xp1[4];
      {
        const half_t* hx = &hr[nxt][l16&3][0];
        half8 xb[4];
        #pragma unroll
        for (int kc=0; kc<4; kc++) xb[kc] = *(const half8*)(hx + kc*32 + quad*8);
        #pragma unroll
        for (int nt=0; nt<4; nt++) {
          floatx4 a = __builtin_amdgcn_mfma_f32_16x16x32_f16(xb[0], wxF[nt][0], z4, 0,0,0);
          a = __builtin_amdgcn_mfma_f32_16x16x32_f16(xb[1], wxF[nt][1], a, 0,0,0);
          a = __builtin_amdgcn_mfma_f32_16x16x32_f16(xb[2], wxF[nt][2], a, 0,0,0);
          xp1[nt] = __builtin_amdgcn_mfma_f32_16x16x32_f16(xb[3], wxF[nt][3], a, 0,0,0);
        }
      }
      floatx4 bh[4];
      {
        const half_t* h1r = &h2[nxt][l16&3][0];
        half8 hb[4];
        #pragma unroll
        for (int kc=0; kc<4; kc++) hb[kc] = *(const half8*)(h1r + kc*32 + quad*8);
        #pragma unroll
        for (int nt=0; nt<4; nt++) {
          floatx4 a = __builtin_amdgcn_mfma_f32_16x16x32_f16(hb[0], whF[nt][0], xp1[nt], 0,0,0);
          a = __builtin_amdgcn_mfma_f32_16x16x32_f16(hb[1], whF[nt][1], a, 0,0,0);
          a = __builtin_amdgcn_mfma_f32_16x16x32_f16(hb[2], whF[nt][2], a, 0,0,0);
          bh[nt] = __builtin_amdgcn_mfma_f32_16x16x32_f16(hb[3], whF[nt][3], a, 0,0,0);
        }
      }
      const float gi = bh[0][quad] + bias1[0];
      const float gf = bh[1][quad] + bias1[1];
      const float gg = bh[2][quad] + bias1[2];
      const float go = bh[3][quad] + bias1[3];
      cst1 = fsig(gf)*cst1 + fsig(gi)*ftanh(gg);
      h2[cur][quad][colw] = (half_t)(fsig(go)*ftanh(cst1));
    }
    __syncthreads();
  }

  // ---- FC (60 classes) + softmax; h1(299) is in h2[0] (interval 300 wrote cur=0)
  if (tid < 240) {
    const int rr = tid/60, cls = tid%60;
    float s = fcb[cls];
    for (int k2=0; k2<128; k2++) s += (float)h2[0][rr][k2] * fcw[cls*128+k2];
    logits[rr*60+cls] = s;
  }
  __syncthreads();
  if (tid < 4) {
    float m = -1e30f;
    for (int j=0; j<60; j++) m = fmaxf(m, logits[tid*60+j]);
    float s = 0.f;
    for (int j=0; j<60; j++) s += __expf(logits[tid*60+j]-m);
    const float inv = frcp(s);
    for (int j=0; j<60; j++) out[(nm0+tid)*60+j] = __expf(logits[tid*60+j]-m)*inv;
  }
}

extern "C" void kernel_launch(void* const* d_in, const int* in_sizes, int n_in,
                              void* d_out, int out_size, void* d_ws, size_t ws_size,
                              hipStream_t stream) {
  const float* x1      = (const float*)d_in[0];
  const float* cheb_w0 = (const float*)d_in[2];
  const float* cheb_w1 = (const float*)d_in[3];
  const float* cheb_b  = (const float*)d_in[4];
  const float* wih0    = (const float*)d_in[5];
  const float* whh0    = (const float*)d_in[6];
  const float* bih0    = (const float*)d_in[7];
  const float* bhh0    = (const float*)d_in[8];
  const float* wih1    = (const float*)d_in[9];
  const float* whh1    = (const float*)d_in[10];
  const float* bih1    = (const float*)d_in[11];
  const float* bhh1    = (const float*)d_in[12];
  const float* fc_w    = (const float*)d_in[13];
  const float* fc_b    = (const float*)d_in[14];

  char* ws = (char*)d_ws;
  half_t* xt  = (half_t*)(ws + XT_OFF);
  half_t* wch = (half_t*)(ws + WCH_OFF);

  k_prep <<<dim3(1),     dim3(512), 0, stream>>>(cheb_w0, cheb_w1, cheb_b, wih0, bih0, bhh0, wch);
  k_xpose<<<dim3(27000), dim3(256), 0, stream>>>(x1, xt);
  k_lstm_m<<<dim3(256),  dim3(512), 0, stream>>>(
      xt, wch, whh0, wih1, whh1, bih1, bhh1, fc_w, fc_b, (float*)d_out);
}

// Round 9
// 426.006 us; speedup vs baseline: 1.4833x; 1.4833x over previous
//
#include <hip/hip_runtime.h>
#include <hip/hip_fp16.h>

typedef _Float16 half_t;
typedef _Float16 half8 __attribute__((ext_vector_type(8)));
typedef float floatx4 __attribute__((ext_vector_type(4)));
typedef int   int4v  __attribute__((ext_vector_type(4)));

// ---- sizes ----
#define T_STEPS 300
#define NMB     1024                 // N*M batch
#define BS      16                   // steps per staged block
#define NBLK    19                   // ceil(300/16)

// LDS geometry (R7-measured layout, kept identical)
#define XP0   88
#define XROW0 (8*XP0 + 8)
#define HP    152
#define XROW1 (8*HP + 8)
#define HSLOT (8*HP)

// ws layout (bytes)
#define XT_OFF   0ULL
#define XT_BYTES ((unsigned long long)(T_STEPS*NMB + 16)*64*2)
#define HS0_OFF  (XT_OFF + XT_BYTES)
#define HS0_BYTES ((unsigned long long)(T_STEPS*NMB + 16)*128*2)
#define WCH_OFF  (HS0_OFF + HS0_BYTES)        // wcomb as f16 [512][64]
#define WCH_BYTES (512ULL*64*2)
#define BC_OFF   (WCH_OFF + WCH_BYTES)        // biasc f32 [512]
#define BC_BYTES (512ULL*4)
#define FLAG_OFF (BC_OFF + BC_BYTES)          // flags, 64B stride

// L_hat = -D^-1/2 A D^-1/2 for the hardcoded 15-node skeleton (row=dst, col=src)
#define S2 0.70710678118654752f
#define QH 0.5f
#define UU 0.40824829046386302f
#define TH 0.33333333333333333f
__constant__ float LHAT[225] = {
  0,0,-S2,0,0,0,0,0,0,0,0,0,0,0,0,
  0,0,0,-S2,0,0,0,0,0,0,0,0,0,0,0,
  -S2,0,0,0,-QH,0,0,0,0,0,0,0,0,0,0,
  0,-S2,0,0,0,-QH,0,0,0,0,0,0,0,0,0,
  0,0,-QH,0,0,0,0,0,0,0,0,0,0,0,-UU,
  0,0,0,-QH,0,0,0,0,0,0,0,0,0,0,-UU,
  0,0,0,0,0,0,0,0,-S2,0,0,0,0,0,0,
  0,0,0,0,0,0,0,0,0,-S2,0,0,0,0,0,
  0,0,0,0,0,0,-S2,0,0,0,-QH,0,0,0,0,
  0,0,0,0,0,0,0,-S2,0,0,0,-QH,0,0,0,
  0,0,0,0,0,0,0,0,-QH,0,0,0,0,-UU,0,
  0,0,0,0,0,0,0,0,0,-QH,0,0,0,-UU,0,
  0,0,0,0,0,0,0,0,0,0,0,0,0,0,0,
  0,0,0,0,0,0,0,0,0,0,-UU,-UU,0,0,0,
  0,0,0,0,-UU,-UU,0,0,0,0,0,0,0,-TH,0
};

// Fast gate math: v_exp_f32 + v_rcp_f32 (approx, ~1 ulp).
__device__ __forceinline__ float frcp(float x)  { return __builtin_amdgcn_rcpf(x); }
__device__ __forceinline__ float fsig(float x)  { return frcp(1.f + __expf(-x)); }
__device__ __forceinline__ float ftanh(float x) { return 2.f*frcp(1.f + __expf(-2.f*x)) - 1.f; }

__device__ __forceinline__ half8 load_w8(const float* p) {
  const float4* q = (const float4*)p;
  float4 a = q[0], b = q[1];
  half8 f;
  f[0]=(half_t)a.x; f[1]=(half_t)a.y; f[2]=(half_t)a.z; f[3]=(half_t)a.w;
  f[4]=(half_t)b.x; f[5]=(half_t)b.y; f[6]=(half_t)b.z; f[7]=(half_t)b.w;
  return f;
}

// Force true register residency of fragments (kills per-step remat).
__device__ __forceinline__ void pin(half8& f) {
  int4v t = __builtin_bit_cast(int4v, f);
  asm volatile("" : "+v"(t));
  f = __builtin_bit_cast(half8, t);
}
__device__ __forceinline__ void pinf(floatx4& f) {
  int4v t = __builtin_bit_cast(int4v, f);
  asm volatile("" : "+v"(t));
  f = __builtin_bit_cast(floatx4, t);
}

// Consumer-side block gate: relaxed poll + one acquire.
__device__ __forceinline__ void wait_flag(const int* f, int want, int tid) {
  if (tid == 0) {
    while (__hip_atomic_load(f, __ATOMIC_RELAXED, __HIP_MEMORY_SCOPE_AGENT) < want)
      __builtin_amdgcn_s_sleep(8);
    (void)__hip_atomic_load(f, __ATOMIC_ACQUIRE, __HIP_MEMORY_SCOPE_AGENT);
  }
  __syncthreads();
}

// ---- K0: fold ChebConv into layer-0 input projection: wcomb_h f16[512][64], biasc[512]
// Also zeroes the producer->consumer block flags (must happen every replay).
__global__ void k_prep(const float* __restrict__ w0, const float* __restrict__ w1,
                       const float* __restrict__ cb, const float* __restrict__ wih0,
                       const float* __restrict__ bih0, const float* __restrict__ bhh0,
                       half_t* __restrict__ wcomb_h, float* __restrict__ biasc,
                       int* __restrict__ flags) {
  const int n = threadIdx.x; // 512 threads, 1 block
  if (n < 256) flags[n*16] = 0;
  float wrow[45];
  #pragma unroll
  for (int i=0;i<45;i++) wrow[i] = wih0[n*45+i];
  float P[45];
  #pragma unroll
  for (int i=0;i<15;i++)
    #pragma unroll
    for (int c=0;c<3;c++) {
      float s = 0.f;
      #pragma unroll
      for (int cp=0;cp<3;cp++) s += wrow[i*3+cp]*w1[cp*3+c];
      P[i*3+c] = s;
    }
  #pragma unroll
  for (int j=0;j<15;j++)
    #pragma unroll
    for (int c=0;c<3;c++) {
      float s = 0.f;
      #pragma unroll
      for (int cp=0;cp<3;cp++) s += wrow[j*3+cp]*w0[cp*3+c];
      #pragma unroll
      for (int i=0;i<15;i++) s += LHAT[i*15+j]*P[i*3+c];
      wcomb_h[n*64 + j*3+c] = (half_t)s;
    }
  for (int k=45;k<64;k++) wcomb_h[n*64+k] = (half_t)0.f;
  float b = bih0[n] + bhh0[n];
  #pragma unroll
  for (int i=0;i<15;i++)
    #pragma unroll
    for (int cp=0;cp<3;cp++) b += wrow[i*3+cp]*cb[cp];
  biasc[n] = b;
}

// ---- Fused LSTM on DISJOINT CUs (R7 structure, measured 315us fused).
// R9 change: XPROJ DOUBLE-BUFFER PIPELINING (R1-proven) — group g+1's xproj MFMAs
// are issued at the start of group g, so the h-chains of group g (which C-init
// from xpA computed one group earlier) never wait on the xproj dependency chain.
// Ping-pong via 2-unrolled group loop (ngr is always even: 8 or 6) -> no copies.
// R8 lesson kept: merged-WG M=4 doubles MFMA work; disjoint-CU M=8 stays.
__launch_bounds__(512, 1)
__global__ void k_lstm_fused(const float* __restrict__ x1, const half_t* __restrict__ wch,
                             const float* __restrict__ biasc, const float* __restrict__ whh0,
                             half_t* __restrict__ hs0,
                             const float* __restrict__ wih1, const float* __restrict__ whh1,
                             const float* __restrict__ bih1, const float* __restrict__ bhh1,
                             const float* __restrict__ fcw, const float* __restrict__ fcb,
                             float* __restrict__ out, int* __restrict__ flags) {
  __shared__ __align__(16) char smem[85120];
  half_t* S = (half_t*)smem;
  const int tid = threadIdx.x;
  const int wave = tid>>6, lane = tid&63, quad = lane>>4, l16 = lane&15;
  const int colw = wave*16 + l16;              // owned h column (0..127)

  if (blockIdx.x < 128) {
    // ================= layer-0 producer (8 rows, inline x-transpose) =============
    half_t* XS = S;                   // [2][16][XROW0]
    half_t* HR = S + 2*BS*XROW0;      // [16][HSLOT]
    const int wg  = blockIdx.x;
    const int nm0 = wg*8;
    const int n0t3 = wg*4*3;
    int* flag = flags + wg*16;

    for (int i=tid; i<2*BS*XROW0; i+=512) XS[i] = (half_t)0.f;
    for (int i=tid; i<HSLOT; i+=512) HR[15*HSLOT + i] = (half_t)0.f;

    half8 whhF[4][4]; half8 wcF[4][2]; floatx4 biasv[4];
    #pragma unroll
    for (int nt=0; nt<4; nt++) {
      const int gcol = nt*128 + colw;
      #pragma unroll
      for (int kc=0; kc<4; kc++) { whhF[nt][kc] = load_w8(whh0 + gcol*128 + kc*32 + quad*8); pin(whhF[nt][kc]); }
      #pragma unroll
      for (int kc=0; kc<2; kc++) { wcF[nt][kc] = *(const half8*)(wch + gcol*64 + kc*32 + quad*8); pin(wcF[nt][kc]); }
      const float b = biasc[gcol];
      biasv[nt] = (floatx4){b,b,b,b}; pinf(biasv[nt]);
    }
    float cst0 = 0.f, cst1 = 0.f;

    float2 xld[6];
    #define XLOAD(TBASE) { _Pragma("unroll") for (int k=0;k<6;k++) {          \
        const int idx=k*512+tid; const int v_=idx&15;                          \
        if (v_<15) { const int sh_=(idx>>4)&15; const int rB_=idx>>8;          \
          int tt=(TBASE)+sh_; if (tt>299) tt=299;                              \
          xld[k]=((const float2*)x1)[(size_t)((n0t3+rB_)*300+tt)*15+v_]; } } }
    #define XWRITE(BUFI) { _Pragma("unroll") for (int k=0;k<6;k++) {          \
        const int idx=k*512+tid; const int v_=idx&15;                          \
        if (v_<15) { const int sh_=(idx>>4)&15; const int rB_=idx>>8;          \
          const int nh_=rB_/3, c_=rB_-3*(rB_/3);                               \
          half_t* w = XS + ((BUFI)*BS + sh_)*XROW0 + nh_*2*XP0 + v_*3+c_;      \
          w[0]   = (half_t)xld[k].x;                                           \
          w[XP0] = (half_t)xld[k].y; } } }

    // xproj compute into DST from row pointer PTR (K=64: 2 kc), C-init biasv
    #define XP0COMP(DST, PTR) {                                                \
      const half8 xa0 = *(const half8*)((PTR) + quad*8);                       \
      const half8 xa1 = *(const half8*)((PTR) + 32 + quad*8);                  \
      _Pragma("unroll") for (int nt=0; nt<4; nt++) {                           \
        floatx4 a_ = __builtin_amdgcn_mfma_f32_16x16x32_f16(xa0, wcF[nt][0], biasv[nt], 0,0,0); \
        DST[nt]    = __builtin_amdgcn_mfma_f32_16x16x32_f16(xa1, wcF[nt][1], a_, 0,0,0); } }

    // one 2-step group body: uses XPU (this group's xproj), computes XPN (next's)
    #define GROUP0(G, XPU, XPN) {                                              \
      const int s0 = (G)*2;                                                    \
      const int ns = s0+2;                                                     \
      const half_t* nxrow = (ns < cnt)                                         \
          ? XS + (buf*BS + ns + (l16&1))*XROW0 + (l16>>1)*XP0                  \
          : XS + (((buf^1)*BS) + (l16&1))*XROW0 + (l16>>1)*XP0;                \
      XP0COMP(XPN, nxrow);                                                     \
      _Pragma("unroll") for (int js=0; js<2; js++) {                           \
        const int t = bs + s0 + js;                                            \
        if (js==1 && (G)==0 && b+1 < NBLK) XWRITE(buf^1);                      \
        floatx4 ah[4];                                                         \
        {                                                                      \
          const half_t* hrow = HR + ((t+15)&15)*HSLOT + (l16>>1)*HP;           \
          half8 ha[4];                                                         \
          _Pragma("unroll") for (int kc=0; kc<4; kc++) ha[kc] = *(const half8*)(hrow + kc*32 + quad*8); \
          _Pragma("unroll") for (int nt=0; nt<4; nt++) {                       \
            floatx4 a_ = __builtin_amdgcn_mfma_f32_16x16x32_f16(ha[0], whhF[nt][0], XPU[nt], 0,0,0); \
            a_ = __builtin_amdgcn_mfma_f32_16x16x32_f16(ha[1], whhF[nt][1], a_, 0,0,0); \
            a_ = __builtin_amdgcn_mfma_f32_16x16x32_f16(ha[2], whhF[nt][2], a_, 0,0,0); \
            ah[nt] = __builtin_amdgcn_mfma_f32_16x16x32_f16(ha[3], whhF[nt][3], a_, 0,0,0); } \
        }                                                                      \
        _Pragma("unroll") for (int bb=0; bb<2; bb++) {                         \
          const int r = bb*2 + js;                                             \
          float& cst = bb ? cst1 : cst0;                                       \
          cst = fsig(ah[1][r])*cst + fsig(ah[0][r])*ftanh(ah[2][r]);           \
          HR[(t&15)*HSLOT + (quad*2+bb)*HP + colw] = (half_t)(fsig(ah[3][r])*ftanh(cst)); \
        }                                                                      \
        __syncthreads();                                                       \
      } }

    XLOAD(0); __syncthreads(); XWRITE(0);
    __syncthreads();

    floatx4 xpA[4], xpB[4];
    XP0COMP(xpA, XS + (l16&1)*XROW0 + (l16>>1)*XP0);   // block 0, group 0

    for (int b=0; b<NBLK; b++) {
      const int bs = b*BS, buf = b&1;
      const int cnt = (T_STEPS - bs < BS) ? (T_STEPS - bs) : BS;
      const int ngr = cnt>>1;                 // 8 or 6 (even)
      if (b+1 < NBLK) XLOAD(bs + BS);
      for (int g=0; g<ngr; g+=2) {
        GROUP0(g,   xpA, xpB);
        GROUP0(g+1, xpB, xpA);
      }
      {
        const int hS = tid>>5, hR = (tid>>2)&7, hC = (tid&3)*32;
        if (hS < cnt) {
          half_t* dst = hs0 + ((size_t)(bs+hS)*NMB + nm0 + hR)*128 + hC;
          const half_t* src = HR + ((bs+hS)&15)*HSLOT + hR*HP + hC;
          #pragma unroll
          for (int k=0;k<4;k++) *(half8*)(dst + k*8) = *(const half8*)(src + k*8);
        }
      }
      __syncthreads();
      if (tid == 0)
        __hip_atomic_store(flag, b+1, __ATOMIC_RELEASE, __HIP_MEMORY_SCOPE_AGENT);
    }
  } else {
    // ================= layer-1 consumer (8 rows) + FC/softmax ====================
    half_t* XS = S;                   // [2][16][XROW1]
    half_t* H2 = S + 2*BS*XROW1;      // [2][HSLOT]
    float* logits_lds = (float*)(smem + (2*BS*XROW1 + 2*HSLOT)*2);  // 480 f32
    const int wg  = blockIdx.x - 128;
    const int nm0 = wg*8;
    const int* flag = flags + wg*16;

    for (int i=tid; i<2*HSLOT; i+=512) H2[i] = (half_t)0.f;

    half8 whF[4][4], wxF[4][4]; floatx4 biasv[4];
    #pragma unroll
    for (int nt=0; nt<4; nt++) {
      const int gcol = nt*128 + colw;
      #pragma unroll
      for (int kc=0; kc<4; kc++) {
        wxF[nt][kc] = load_w8(wih1 + gcol*128 + kc*32 + quad*8); pin(wxF[nt][kc]);
        whF[nt][kc] = load_w8(whh1 + gcol*128 + kc*32 + quad*8); pin(whF[nt][kc]);
      }
      const float b = bih1[gcol] + bhh1[gcol];
      biasv[nt] = (floatx4){b,b,b,b}; pinf(biasv[nt]);
    }
    float cst0 = 0.f, cst1 = 0.f;

    const int sS = tid>>5, sR = (tid>>2)&7, sC = (tid&3)*32;
    const int coff = sS*XROW1 + sR*HP + sC;
    float4 ld[4];

    #define XP1COMP(DST, PTR) {                                                \
      half8 xa[4];                                                             \
      _Pragma("unroll") for (int kc=0; kc<4; kc++) xa[kc] = *(const half8*)((PTR) + kc*32 + quad*8); \
      _Pragma("unroll") for (int nt=0; nt<4; nt++) {                           \
        floatx4 a_ = __builtin_amdgcn_mfma_f32_16x16x32_f16(xa[0], wxF[nt][0], biasv[nt], 0,0,0); \
        a_ = __builtin_amdgcn_mfma_f32_16x16x32_f16(xa[1], wxF[nt][1], a_, 0,0,0); \
        a_ = __builtin_amdgcn_mfma_f32_16x16x32_f16(xa[2], wxF[nt][2], a_, 0,0,0); \
        DST[nt] = __builtin_amdgcn_mfma_f32_16x16x32_f16(xa[3], wxF[nt][3], a_, 0,0,0); } }

    #define GROUP1(G, XPU, XPN) {                                              \
      const int s0 = (G)*2;                                                    \
      const int ns = s0+2;                                                     \
      const half_t* nxrow = (ns < cnt)                                         \
          ? XS + (buf*BS + ns + (l16&1))*XROW1 + (l16>>1)*HP                   \
          : XS + (((buf^1)*BS) + (l16&1))*XROW1 + (l16>>1)*HP;                 \
      XP1COMP(XPN, nxrow);                                                     \
      _Pragma("unroll") for (int js=0; js<2; js++) {                           \
        const int t = bs + s0 + js;                                            \
        if (js==1 && (G)==0 && b+1 < NBLK) {                                   \
          _Pragma("unroll")                                                    \
          for (int k=0;k<4;k++) *(half8*)(XS + ((buf^1)*BS)*XROW1 + coff + k*8) = __builtin_bit_cast(half8, ld[k]); \
        }                                                                      \
        floatx4 ah[4];                                                         \
        {                                                                      \
          const half_t* hrow = H2 + (t&1)*HSLOT + (l16>>1)*HP;                 \
          half8 ha[4];                                                         \
          _Pragma("unroll") for (int kc=0; kc<4; kc++) ha[kc] = *(const half8*)(hrow + kc*32 + quad*8); \
          _Pragma("unroll") for (int nt=0; nt<4; nt++) {                       \
            floatx4 a_ = __builtin_amdgcn_mfma_f32_16x16x32_f16(ha[0], whF[nt][0], XPU[nt], 0,0,0); \
            a_ = __builtin_amdgcn_mfma_f32_16x16x32_f16(ha[1], whF[nt][1], a_, 0,0,0); \
            a_ = __builtin_amdgcn_mfma_f32_16x16x32_f16(ha[2], whF[nt][2], a_, 0,0,0); \
            ah[nt] = __builtin_amdgcn_mfma_f32_16x16x32_f16(ha[3], whF[nt][3], a_, 0,0,0); } \
        }                                                                      \
        _Pragma("unroll") for (int bb=0; bb<2; bb++) {                         \
          const int r = bb*2 + js;                                             \
          float& cst = bb ? cst1 : cst0;                                       \
          cst = fsig(ah[1][r])*cst + fsig(ah[0][r])*ftanh(ah[2][r]);           \
          H2[((t+1)&1)*HSLOT + (quad*2+bb)*HP + colw] = (half_t)(fsig(ah[3][r])*ftanh(cst)); \
        }                                                                      \
        __syncthreads();                                                       \
      } }

    wait_flag(flag, 1, tid);
    { const half_t* src = hs0 + ((size_t)sS*NMB + nm0 + sR)*128 + sC;
      #pragma unroll
      for (int k=0;k<4;k++) ld[k] = *(const float4*)(src + k*8); }
    #pragma unroll
    for (int k=0;k<4;k++) *(half8*)(XS + coff + k*8) = __builtin_bit_cast(half8, ld[k]);
    __syncthreads();

    floatx4 xpA[4], xpB[4];
    XP1COMP(xpA, XS + (l16&1)*XROW1 + (l16>>1)*HP);    // block 0, group 0

    for (int b=0; b<NBLK; b++) {
      const int bs = b*BS, buf = b&1;
      const int cnt = (T_STEPS - bs < BS) ? (T_STEPS - bs) : BS;
      const int ngr = cnt>>1;
      if (b+1 < NBLK) {
        wait_flag(flag, b+2, tid);
        int tt = bs + BS + sS; if (tt > 299) tt = 299;
        const half_t* src = hs0 + ((size_t)tt*NMB + nm0 + sR)*128 + sC;
        #pragma unroll
        for (int k=0;k<4;k++) ld[k] = *(const float4*)(src + k*8);
      }
      for (int g=0; g<ngr; g+=2) {
        GROUP1(g,   xpA, xpB);
        GROUP1(g+1, xpB, xpA);
      }
    }

    // ---- FC (60 classes) + softmax; h1[299] in H2 buffer 0, rows 0..7
    if (tid < 480) {
      const int rr = tid/60, cls = tid%60;
      float s = fcb[cls];
      for (int k2=0; k2<128; k2++) s += (float)H2[rr*HP + k2] * fcw[cls*128+k2];
      logits_lds[rr*60+cls] = s;
    }
    __syncthreads();
    if (tid < 8) {
      float m = -1e30f;
      for (int j=0; j<60; j++) m = fmaxf(m, logits_lds[tid*60+j]);
      float s = 0.f;
      for (int j=0; j<60; j++) s += __expf(logits_lds[tid*60+j]-m);
      const float inv = frcp(s);
      for (int j=0; j<60; j++) out[(nm0+tid)*60+j] = __expf(logits_lds[tid*60+j]-m)*inv;
    }
  }
}

extern "C" void kernel_launch(void* const* d_in, const int* in_sizes, int n_in,
                              void* d_out, int out_size, void* d_ws, size_t ws_size,
                              hipStream_t stream) {
  const float* x1      = (const float*)d_in[0];
  const float* cheb_w0 = (const float*)d_in[2];
  const float* cheb_w1 = (const float*)d_in[3];
  const float* cheb_b  = (const float*)d_in[4];
  const float* wih0    = (const float*)d_in[5];
  const float* whh0    = (const float*)d_in[6];
  const float* bih0    = (const float*)d_in[7];
  const float* bhh0    = (const float*)d_in[8];
  const float* wih1    = (const float*)d_in[9];
  const float* whh1    = (const float*)d_in[10];
  const float* bih1    = (const float*)d_in[11];
  const float* bhh1    = (const float*)d_in[12];
  const float* fc_w    = (const float*)d_in[13];
  const float* fc_b    = (const float*)d_in[14];

  char* ws = (char*)d_ws;
  half_t* hs0   = (half_t*)(ws + HS0_OFF);
  half_t* wch   = (half_t*)(ws + WCH_OFF);
  float*  biasc = (float*)(ws + BC_OFF);
  int*    flags = (int*)(ws + FLAG_OFF);

  k_prep<<<dim3(1), dim3(512), 0, stream>>>(cheb_w0, cheb_w1, cheb_b, wih0, bih0, bhh0, wch, biasc, flags);
  k_lstm_fused<<<dim3(256), dim3(512), 0, stream>>>(
      x1, wch, biasc, whh0, hs0, wih1, whh1, bih1, bhh1, fc_w, fc_b, (float*)d_out, flags);
}